// Round 8
// baseline (345.760 us; speedup 1.0000x reference)
//
#include <hip/hip_runtime.h>
#include <cstdint>

typedef float f32x4 __attribute__((ext_vector_type(4)));
typedef __bf16 bf16x8 __attribute__((ext_vector_type(8)));
typedef unsigned short u16x8 __attribute__((ext_vector_type(8)));

typedef __attribute__((address_space(3))) uint32_t lds_u32;
typedef __attribute__((address_space(1))) const uint32_t glb_u32;

// async 16B global->LDS: dest = wave-uniform base + lane*16
#define GLOAD_LDS16(gp, lp) \
  __builtin_amdgcn_global_load_lds((glb_u32*)(uintptr_t)(gp), (lds_u32*)(uintptr_t)(lp), 16, 0, 0)

__device__ inline unsigned short f2bf(float f) {
  union { float f; uint32_t u; } v; v.f = f;
  uint32_t u = v.u;
  return (unsigned short)((u + 0x7fffu + ((u >> 16) & 1u)) >> 16); // RNE
}

// ---------------------------------------------------------------------------
// K1: transpose + bf16-cast the 4 weight matrices: Wt[n][k] = bf16(W[k][n])
// ---------------------------------------------------------------------------
__global__ void prep_w(const float* __restrict__ wq, const float* __restrict__ wk,
                       const float* __restrict__ wv, const float* __restrict__ wo,
                       unsigned short* __restrict__ wt)
{
  __shared__ float t[64][65];
  const int z = blockIdx.z;
  const float* W = (z == 0) ? wq : (z == 1) ? wk : (z == 2) ? wv : wo;
  unsigned short* Wt = wt + (size_t)z * 1048576;
  const int n0 = blockIdx.x * 64, k0 = blockIdx.y * 64;
  const int tx = threadIdx.x & 63, ty = threadIdx.x >> 6;
#pragma unroll
  for (int i = 0; i < 16; i++) {
    int row = i * 4 + ty;
    t[row][tx] = W[(size_t)(k0 + row) * 1024 + n0 + tx];
  }
  __syncthreads();
#pragma unroll
  for (int i = 0; i < 16; i++) {
    int row = i * 4 + ty;
    Wt[(size_t)(n0 + row) * 1024 + k0 + tx] = f2bf(t[tx][row]);
  }
}

// ---------------------------------------------------------------------------
// K1b: compose the two RoPE tables into one rotation table (128 pos x 32 pairs)
// ---------------------------------------------------------------------------
__global__ void comb_kernel(const float* __restrict__ ing, const float* __restrict__ seq,
                            float* __restrict__ cosc, float* __restrict__ sinc)
{
  int idx = blockIdx.x * 256 + threadIdx.x; // 0..4095
  int j = idx >> 5, i = idx & 31;
  float s1 = ing[j * 64 + i], c1 = ing[j * 64 + 32 + i];
  float s2 = seq[j * 64 + i], c2 = seq[j * 64 + 32 + i];
  cosc[idx] = c1 * c2 - s1 * s2;   // cos(t1+t2)
  sinc[idx] = s1 * c2 + c1 * s2;   // sin(t1+t2)
}

// ---------------------------------------------------------------------------
// K3: QKV projection GEMM, 128x128 tile, BK=64. NEW vs round 7: A is staged
// DIRECTLY as fp32 from the input tensors (cvt_kernel deleted — saves its
// 96MB read + 48MB write round-trip and one launch). A-tile = 32KB fp32,
// 16B granules (4 floats), both-sides XOR swizzle over 16 granules/row;
// fragments converted fp32->bf16 in-register (RNE, identical numerics to the
// old cvt path). B stays bf16 from prep_w. Epilogue = round-7 validated
// LDS-bounce coalesced store (z<2 LDS-write XOR upgraded <<3 -> <<4 so quads
// land on disjoint 8-bank groups: kills the residual 917K conflicts).
// ---------------------------------------------------------------------------
__global__ __launch_bounds__(256, 2)
void gemm_qkv(const float* __restrict__ qf, const float* __restrict__ kf,
              const float* __restrict__ vf,
              const unsigned short* __restrict__ Bbase,
              const float* __restrict__ b0, const float* __restrict__ b1,
              const float* __restrict__ b2,
              unsigned short* __restrict__ qb, unsigned short* __restrict__ kb,
              unsigned short* __restrict__ vtb,
              const float* __restrict__ cosc, const float* __restrict__ sinc)
{
  __shared__ __attribute__((aligned(16))) float Asf[8192];          // 32KB
  __shared__ __attribute__((aligned(16))) unsigned short Bs[8192];  // 16KB

  const int tid = threadIdx.x;
  const int lane = tid & 63;
  const int wave = tid >> 6;
  const int quad = lane >> 4;
  const int l15 = lane & 15;

  const int z = blockIdx.z;
  const int tileM = blockIdx.x * 128;   // M fastest -> XCD-local A reuse
  const int tileN = blockIdx.y * 128;
  const int K = 1024;

  const float* A = (z == 0) ? qf : (z == 1) ? kf : vf;
  const unsigned short* B = Bbase + (size_t)z * (1024u * 1024u);

  const int wm = (wave >> 1) * 64;
  const int wn = (wave & 1) * 64;

  f32x4 acc[4][4];
#pragma unroll
  for (int a = 0; a < 4; a++)
#pragma unroll
    for (int n = 0; n < 4; n++)
      acc[a][n] = (f32x4){0.f, 0.f, 0.f, 0.f};

  for (int k0 = 0; k0 < K; k0 += 64) {
    // ---- stage A fp32: 128 rows x 16 granules(4 floats); 8 granules/thread.
    // LDS slot (row, sc=lane&15) holds logical granule gc = sc ^ (row&15),
    // so read of logical L uses slot L ^ (r&15).
#pragma unroll
    for (int cc = 0; cc < 8; cc++) {
      int c = wave * 8 + cc;            // 0..31, wave-uniform
      int g = c * 64 + lane;            // granule slot 0..2047
      int row = g >> 4;                 // = c*4 + quad
      int gc = (g & 15) ^ (row & 15);   // pre-swizzled source granule col
      const float* ga = A + (size_t)(tileM + row) * 1024 + k0 + gc * 4;
      GLOAD_LDS16(ga, &Asf[c * 256]);
    }
    // ---- stage B bf16 (unchanged scheme: 8 granules of 8 bf16 per row)
#pragma unroll
    for (int cc = 0; cc < 4; cc++) {
      int c = wave * 4 + cc;
      int s = c * 64 + lane;
      int row = s >> 3;
      int gc = (s & 7) ^ (row & 7);
      const unsigned short* gb = B + (size_t)(tileN + row) * K + k0 + gc * 8;
      GLOAD_LDS16(gb, &Bs[c * 512]);
    }
    __syncthreads();   // compiler inserts vmcnt(0) drain before barrier

#pragma unroll
    for (int ks = 0; ks < 2; ks++) {
      bf16x8 af[4], bfr[4];
#pragma unroll
      for (int a = 0; a < 4; a++) {
        int r = wm + a * 16 + l15;
        int L0 = ks * 8 + quad * 2;                 // logical granules L0,L0+1
        f32x4 fa = *(const f32x4*)&Asf[(r * 16 + (L0 ^ l15)) * 4];
        f32x4 fb = *(const f32x4*)&Asf[(r * 16 + ((L0 + 1) ^ l15)) * 4];
        af[a] = (bf16x8){(__bf16)fa[0], (__bf16)fa[1], (__bf16)fa[2], (__bf16)fa[3],
                         (__bf16)fb[0], (__bf16)fb[1], (__bf16)fb[2], (__bf16)fb[3]};
      }
#pragma unroll
      for (int n = 0; n < 4; n++) {
        int r = wn + n * 16 + l15;
        int cp = (ks * 4 + quad) ^ (r & 7);
        bfr[n] = *(const bf16x8*)&Bs[(r * 8 + cp) * 8];
      }
#pragma unroll
      for (int a = 0; a < 4; a++)
#pragma unroll
        for (int n = 0; n < 4; n++)
          acc[a][n] = __builtin_amdgcn_mfma_f32_16x16x32_bf16(af[a], bfr[n], acc[a][n], 0, 0, 0);
    }
    __syncthreads();   // protect LDS for next stage
  }

  // ---- epilogue: LDS-bounce + coalesced store (round-7 validated) ----
  const float* bias = (z == 0) ? b0 : (z == 1) ? b1 : b2;
  unsigned short* outq = (z == 0) ? qb : kb;
  unsigned short* flat = (unsigned short*)Asf;   // 16384 shorts = 32KB

#pragma unroll
  for (int n = 0; n < 4; n++) {
    int lcg = wn + n * 16 + l15;          // 0..127 (local out column)
    float bv_ = bias[tileN + lcg];
    int e = lcg & 63;
#pragma unroll
    for (int a = 0; a < 4; a++)
#pragma unroll
      for (int reg = 0; reg < 4; reg++) {
        int l = wm + a * 16 + quad * 4 + reg;   // 0..127 (local row)
        float v = acc[a][n][reg] + bv_;
        unsigned short ov;
        int f;
        if (z == 2) {
          ov = f2bf(v);
          f = lcg * 128 + l;
          f ^= ((f >> 7) & 15) << 3;          // ~2-way LDS writes
        } else {
          // fused RoPE: cols sit in lane pairs (lane^1 = col^1)
          float other = __shfl_xor(v, 1);
          float cs = cosc[l * 32 + (e >> 1)];
          float sn = sinc[l * 32 + (e >> 1)];
          ov = f2bf(v * cs + ((e & 1) ? other : -other) * sn);
          f = ((lcg >> 6) << 13) + (l << 6) + e;
          f ^= ((f >> 8) & 7) << 4;           // quads -> disjoint 8-bank groups
        }
        flat[f] = ov;
      }
  }
  __syncthreads();

  unsigned short* gout = ((z == 2) ? vtb : outq) +
                         ((size_t)(tileM >> 7) * 16 + (tileN >> 6)) * 8192;
#pragma unroll
  for (int c = 0; c < 8; c++) {
    int f0 = tid * 64 + c * 8;               // chunk-aligned; XOR keeps chunks whole
    int s0 = (z == 2) ? (f0 ^ (((f0 >> 7) & 15) << 3))
                      : (f0 ^ (((f0 >> 8) & 7) << 4));
    *(u16x8*)&gout[f0] = *(const u16x8*)&flat[s0];
  }
}

// ---------------------------------------------------------------------------
// K5: 128x128-tile bf16 GEMM (round-7 validated kernel; used for the output
// projection only, final_mode=1: fp32 out + bias, direct coalesced stores).
// ---------------------------------------------------------------------------
__global__ __launch_bounds__(256, 2)
void gemm_bt(const unsigned short* __restrict__ Abase,
             const unsigned short* __restrict__ Bbase,
             const float* __restrict__ b0, const float* __restrict__ b1,
             const float* __restrict__ b2,
             unsigned short* __restrict__ qb, unsigned short* __restrict__ kb,
             unsigned short* __restrict__ vtb,
             float* __restrict__ outf,
             const float* __restrict__ cosc, const float* __restrict__ sinc,
             int final_mode)
{
  __shared__ __attribute__((aligned(16))) unsigned short Sh[2][8192]; // As | Bs
  unsigned short* As = &Sh[0][0];
  unsigned short* Bs = &Sh[1][0];

  const int tid = threadIdx.x;
  const int lane = tid & 63;
  const int wave = tid >> 6;
  const int quad = lane >> 4;
  const int l15 = lane & 15;

  const int z = blockIdx.z;
  const int tileM = blockIdx.x * 128;
  const int tileN = blockIdx.y * 128;
  const int K = 1024;

  const unsigned short* A = Abase + (size_t)z * (8192u * 1024u);
  const unsigned short* B = Bbase + (size_t)z * (1024u * 1024u);

  const int wm = (wave >> 1) * 64;
  const int wn = (wave & 1) * 64;

  f32x4 acc[4][4];
#pragma unroll
  for (int a = 0; a < 4; a++)
#pragma unroll
    for (int n = 0; n < 4; n++)
      acc[a][n] = (f32x4){0.f, 0.f, 0.f, 0.f};

  for (int k0 = 0; k0 < K; k0 += 64) {
#pragma unroll
    for (int cc = 0; cc < 4; cc++) {
      int c = wave * 4 + cc;
      int s = c * 64 + lane;
      int row = s >> 3;
      int gc = (s & 7) ^ (row & 7);
      const unsigned short* ga = A + (size_t)(tileM + row) * K + k0 + gc * 8;
      const unsigned short* gb = B + (size_t)(tileN + row) * K + k0 + gc * 8;
      GLOAD_LDS16(ga, &As[c * 512]);
      GLOAD_LDS16(gb, &Bs[c * 512]);
    }
    __syncthreads();

#pragma unroll
    for (int ks = 0; ks < 2; ks++) {
      bf16x8 af[4], bfr[4];
#pragma unroll
      for (int a = 0; a < 4; a++) {
        int r = wm + a * 16 + l15;
        int cp = (ks * 4 + quad) ^ (r & 7);
        af[a] = *(const bf16x8*)&As[(r * 8 + cp) * 8];
      }
#pragma unroll
      for (int n = 0; n < 4; n++) {
        int r = wn + n * 16 + l15;
        int cp = (ks * 4 + quad) ^ (r & 7);
        bfr[n] = *(const bf16x8*)&Bs[(r * 8 + cp) * 8];
      }
#pragma unroll
      for (int a = 0; a < 4; a++)
#pragma unroll
        for (int n = 0; n < 4; n++)
          acc[a][n] = __builtin_amdgcn_mfma_f32_16x16x32_bf16(af[a], bfr[n], acc[a][n], 0, 0, 0);
    }
    __syncthreads();
  }

  if (final_mode) {
#pragma unroll
    for (int n = 0; n < 4; n++) {
      int cg = tileN + wn + n * 16 + l15;
      float bias = b0[cg];
#pragma unroll
      for (int a = 0; a < 4; a++)
#pragma unroll
        for (int reg = 0; reg < 4; reg++) {
          int r = tileM + wm + a * 16 + quad * 4 + reg;
          outf[(size_t)r * 1024 + cg] = acc[a][n][reg] + bias;
        }
    }
  } else {
    const float* bias = (z == 0) ? b0 : (z == 1) ? b1 : b2;
    unsigned short* outq = (z == 0) ? qb : kb;
    unsigned short* flat = &Sh[0][0];

#pragma unroll
    for (int n = 0; n < 4; n++) {
      int lcg = wn + n * 16 + l15;
      float bv_ = bias[tileN + lcg];
      int e = lcg & 63;
#pragma unroll
      for (int a = 0; a < 4; a++)
#pragma unroll
        for (int reg = 0; reg < 4; reg++) {
          int l = wm + a * 16 + quad * 4 + reg;
          float v = acc[a][n][reg] + bv_;
          unsigned short ov;
          int f;
          if (z == 2) {
            ov = f2bf(v);
            f = lcg * 128 + l;
            f ^= ((f >> 7) & 15) << 3;
          } else {
            float other = __shfl_xor(v, 1);
            float cs = cosc[l * 32 + (e >> 1)];
            float sn = sinc[l * 32 + (e >> 1)];
            ov = f2bf(v * cs + ((e & 1) ? other : -other) * sn);
            f = ((lcg >> 6) << 13) + (l << 6) + e;
            f ^= ((f >> 8) & 7) << 3;
          }
          flat[f] = ov;
        }
    }
    __syncthreads();

    unsigned short* gout = ((z == 2) ? vtb : outq) +
                           ((size_t)(tileM >> 7) * 16 + (tileN >> 6)) * 8192;
#pragma unroll
    for (int c = 0; c < 8; c++) {
      int f0 = tid * 64 + c * 8;
      int s0 = (z == 2) ? (f0 ^ (((f0 >> 7) & 15) << 3))
                        : (f0 ^ (((f0 >> 8) & 7) << 3));
      *(u16x8*)&gout[f0] = *(const u16x8*)&flat[s0];
    }
  }
}

// ---------------------------------------------------------------------------
// K4: attention. One block per (b,h). Scores in registers, in-register row
// softmax (16-lane shuffle reduce), fp32 attn out, P via LDS into PV MFMA.
// ---------------------------------------------------------------------------
__global__ __launch_bounds__(256, 2)
void attn_kernel(const unsigned short* __restrict__ qb,
                 const unsigned short* __restrict__ kb,
                 const unsigned short* __restrict__ vtb,
                 const unsigned char* __restrict__ mask,
                 float* __restrict__ attn_out,
                 unsigned short* __restrict__ ob)
{
  __shared__ __attribute__((aligned(16))) unsigned short Pb[128 * 136]; // +8 pad
  const int tid = threadIdx.x;
  const int lane = tid & 63;
  const int wave = tid >> 6;
  const int quad = lane >> 4;
  const int l15 = lane & 15;
  const int bh = blockIdx.x;       // b*16 + h
  const int b = bh >> 4;
  const int h = bh & 15;

  const unsigned short* q = qb + (size_t)bh * 128 * 64;
  const unsigned short* k = kb + (size_t)bh * 128 * 64;
  const unsigned short* vt = vtb + (size_t)bh * 64 * 128;

  f32x4 sacc[2][8];
#pragma unroll
  for (int mt = 0; mt < 2; mt++)
#pragma unroll
    for (int nt = 0; nt < 8; nt++)
      sacc[mt][nt] = (f32x4){0.f, 0.f, 0.f, 0.f};

#pragma unroll
  for (int ks = 0; ks < 2; ks++) {
    bf16x8 aq[2], bk[8];
#pragma unroll
    for (int mt = 0; mt < 2; mt++)
      aq[mt] = *(const bf16x8*)&q[(size_t)(wave * 32 + mt * 16 + l15) * 64 + ks * 32 + quad * 8];
#pragma unroll
    for (int nt = 0; nt < 8; nt++)
      bk[nt] = *(const bf16x8*)&k[(size_t)(nt * 16 + l15) * 64 + ks * 32 + quad * 8];
#pragma unroll
    for (int mt = 0; mt < 2; mt++)
#pragma unroll
      for (int nt = 0; nt < 8; nt++)
        sacc[mt][nt] = __builtin_amdgcn_mfma_f32_16x16x32_bf16(aq[mt], bk[nt], sacc[mt][nt], 0, 0, 0);
  }

  const float scale = 0.125f;
#pragma unroll
  for (int mt = 0; mt < 2; mt++) {
#pragma unroll
    for (int reg = 0; reg < 4; reg++) {
      int r = wave * 32 + mt * 16 + quad * 4 + reg;
      const unsigned char* mrow = mask + ((size_t)b * 128 + r) * 128;
      float sv[8];
#pragma unroll
      for (int nt = 0; nt < 8; nt++) {
        float x = sacc[mt][nt][reg] * scale;
        if (mrow[nt * 16 + l15]) x = -__builtin_inff();
        sv[nt] = x;
      }
      float m = sv[0];
#pragma unroll
      for (int nt = 1; nt < 8; nt++) m = fmaxf(m, sv[nt]);
#pragma unroll
      for (int off = 1; off < 16; off <<= 1) m = fmaxf(m, __shfl_xor(m, off));
      float s = 0.f;
#pragma unroll
      for (int nt = 0; nt < 8; nt++) { sv[nt] = __expf(sv[nt] - m); s += sv[nt]; }
#pragma unroll
      for (int off = 1; off < 16; off <<= 1) s += __shfl_xor(s, off);
      float inv = 1.0f / s;
      float* arow = attn_out + ((size_t)bh * 128 + r) * 128;
#pragma unroll
      for (int nt = 0; nt < 8; nt++) {
        float p = sv[nt] * inv;
        arow[nt * 16 + l15] = p;                    // required fp32 attn output
        Pb[r * 136 + nt * 16 + l15] = f2bf(p);      // bf16 P for PV MFMA
      }
    }
  }
  __syncthreads();

  f32x4 oacc[2][4];
#pragma unroll
  for (int mt = 0; mt < 2; mt++)
#pragma unroll
    for (int nt = 0; nt < 4; nt++)
      oacc[mt][nt] = (f32x4){0.f, 0.f, 0.f, 0.f};

#pragma unroll
  for (int ks = 0; ks < 4; ks++) {
    bf16x8 bv[4], ap[2];
#pragma unroll
    for (int nt = 0; nt < 4; nt++)
      bv[nt] = *(const bf16x8*)&vt[(size_t)(nt * 16 + l15) * 128 + ks * 32 + quad * 8];
#pragma unroll
    for (int mt = 0; mt < 2; mt++)
      ap[mt] = *(const bf16x8*)&Pb[(size_t)(wave * 32 + mt * 16 + l15) * 136 + ks * 32 + quad * 8];
#pragma unroll
    for (int mt = 0; mt < 2; mt++)
#pragma unroll
      for (int nt = 0; nt < 4; nt++)
        oacc[mt][nt] = __builtin_amdgcn_mfma_f32_16x16x32_bf16(ap[mt], bv[nt], oacc[mt][nt], 0, 0, 0);
  }

#pragma unroll
  for (int mt = 0; mt < 2; mt++)
#pragma unroll
    for (int nt = 0; nt < 4; nt++)
#pragma unroll
      for (int reg = 0; reg < 4; reg++) {
        int r = wave * 32 + mt * 16 + quad * 4 + reg;   // l
        int e = nt * 16 + l15;
        ob[((size_t)b * 128 + r) * 1024 + h * 64 + e] = f2bf(oacc[mt][nt][reg]);
      }
}

// ---------------------------------------------------------------------------
extern "C" void kernel_launch(void* const* d_in, const int* in_sizes, int n_in,
                              void* d_out, int out_size, void* d_ws, size_t ws_size,
                              hipStream_t stream)
{
  const float* queries = (const float*)d_in[0];
  const float* keys    = (const float*)d_in[1];
  const float* values  = (const float*)d_in[2];
  const unsigned char* mask = (const unsigned char*)d_in[3];
  const float* Wq = (const float*)d_in[4];
  const float* bq = (const float*)d_in[5];
  const float* Wk = (const float*)d_in[6];
  const float* bk = (const float*)d_in[7];
  const float* Wv = (const float*)d_in[8];
  const float* bv = (const float*)d_in[9];
  const float* Wo = (const float*)d_in[10];
  const float* bo = (const float*)d_in[11];
  const float* ping = (const float*)d_in[12];
  const float* pseq = (const float*)d_in[13];

  float* out  = (float*)d_out;           // [8192,1024] fp32
  float* attn = out + 8388608;           // [64,16,128,128] fp32 (64 MB)

  char* ws = (char*)d_ws;
  unsigned short* Wt  = (unsigned short*)(ws);                          // 8 MB
  float* cosc = (float*)(ws + 8388608);                                 // 16 KB
  float* sinc = (float*)(ws + 8388608 + 16384);                         // 16 KB
  unsigned short* qbuf = (unsigned short*)(ws + 8421376);               // 16 MB
  unsigned short* kbuf = (unsigned short*)(ws + 8421376 + 16777216);    // 16 MB
  unsigned short* vtbuf= (unsigned short*)(ws + 8421376 + 2*16777216);  // 16 MB
  unsigned short* obuf = (unsigned short*)(ws + 8421376 + 3*16777216);  // 16 MB

  prep_w<<<dim3(16, 16, 4), 256, 0, stream>>>(Wq, Wk, Wv, Wo, Wt);
  comb_kernel<<<16, 256, 0, stream>>>(ping, pseq, cosc, sinc);
  gemm_qkv<<<dim3(64, 8, 3), 256, 0, stream>>>(queries, keys, values, Wt,
                                               bq, bk, bv,
                                               qbuf, kbuf, vtbuf, cosc, sinc);
  attn_kernel<<<dim3(1024), 256, 0, stream>>>(qbuf, kbuf, vtbuf, mask, attn, obuf);
  gemm_bt<<<dim3(64, 8, 1), 256, 0, stream>>>(obuf, Wt + 3 * 1048576, bo, bo, bo,
                                              qbuf, kbuf, vtbuf, out,
                                              cosc, sinc, 1);
}

// Round 10
// 338.763 us; speedup vs baseline: 1.0207x; 1.0207x over previous
//
#include <hip/hip_runtime.h>
#include <cstdint>

typedef float f32x4 __attribute__((ext_vector_type(4)));
typedef __bf16 bf16x8 __attribute__((ext_vector_type(8)));
typedef unsigned short u16x8 __attribute__((ext_vector_type(8)));

typedef __attribute__((address_space(3))) uint32_t lds_u32;
typedef __attribute__((address_space(1))) const uint32_t glb_u32;

// async 16B global->LDS: dest = wave-uniform base + lane*16
#define GLOAD_LDS16(gp, lp) \
  __builtin_amdgcn_global_load_lds((glb_u32*)(uintptr_t)(gp), (lds_u32*)(uintptr_t)(lp), 16, 0, 0)

__device__ inline unsigned short f2bf(float f) {
  union { float f; uint32_t u; } v; v.f = f;
  uint32_t u = v.u;
  return (unsigned short)((u + 0x7fffu + ((u >> 16) & 1u)) >> 16); // RNE
}

// ---------------------------------------------------------------------------
// K1 (merged): one launch doing three independent jobs, block-partitioned:
//   bx <  24576 : cvt  — fp32->bf16 of Q/K/V inputs (vectorized)
//   bx <  25600 : prep — transpose + bf16-cast the 4 weight matrices
//   else        : comb — compose the two RoPE tables into one rotation table
// Saves 2 launch gaps; jobs are independent and fill the GPU together.
// ---------------------------------------------------------------------------
__global__ void prep_all(const float* __restrict__ q, const float* __restrict__ k,
                         const float* __restrict__ v,
                         const float* __restrict__ wq, const float* __restrict__ wk,
                         const float* __restrict__ wv, const float* __restrict__ wo,
                         const float* __restrict__ ing, const float* __restrict__ seq,
                         unsigned short* __restrict__ dst, unsigned short* __restrict__ wt,
                         float* __restrict__ cosc, float* __restrict__ sinc)
{
  __shared__ float t[64][65];
  const int bx = blockIdx.x;
  const int tid = threadIdx.x;

  if (bx < 24576) {
    // ---- cvt: 3 x 8192 blocks
    int z = bx >> 13;
    int b8 = bx & 8191;
    const float* src = (z == 0) ? q : (z == 1) ? k : v;
    unsigned short* d = dst + (size_t)z * 8388608;
    size_t i = ((size_t)b8 * 256 + tid) * 4;
    float4 f = *(const float4*)&src[i];
    ushort4 o;
    o.x = f2bf(f.x); o.y = f2bf(f.y); o.z = f2bf(f.z); o.w = f2bf(f.w);
    *(ushort4*)&d[i] = o;
  } else if (bx < 25600) {
    // ---- prep_w: 4 x 256 blocks; Wt[n][k] = bf16(W[k][n])
    int pb = bx - 24576;
    int z = pb >> 8;
    int rem = pb & 255;
    const float* W = (z == 0) ? wq : (z == 1) ? wk : (z == 2) ? wv : wo;
    unsigned short* Wt = wt + (size_t)z * 1048576;
    const int n0 = (rem & 15) * 64, k0 = (rem >> 4) * 64;
    const int tx = tid & 63, ty = tid >> 6;
#pragma unroll
    for (int i = 0; i < 16; i++) {
      int row = i * 4 + ty;
      t[row][tx] = W[(size_t)(k0 + row) * 1024 + n0 + tx];
    }
    __syncthreads();
#pragma unroll
    for (int i = 0; i < 16; i++) {
      int row = i * 4 + ty;
      Wt[(size_t)(n0 + row) * 1024 + k0 + tx] = f2bf(t[tx][row]);
    }
  } else {
    // ---- comb: 16 blocks; 128 pos x 32 pairs
    int idx = (bx - 25600) * 256 + tid;   // 0..4095
    int j = idx >> 5, i = idx & 31;
    float s1 = ing[j * 64 + i], c1 = ing[j * 64 + 32 + i];
    float s2 = seq[j * 64 + i], c2 = seq[j * 64 + 32 + i];
    cosc[idx] = c1 * c2 - s1 * s2;   // cos(t1+t2)
    sinc[idx] = s1 * c2 + c1 * s2;   // sin(t1+t2)
  }
}

// ---------------------------------------------------------------------------
// K3/K5: 128x128-tile bf16 GEMM, BK=64, global_load_lds(16B) staging,
// XOR-swizzled LDS granules, 16x16x32 MFMA (round-7 validated structure).
// Epilogues all bounce through the freed 32KB LDS for coalesced stores:
//   final_mode=0: Q(+RoPE)/K(+RoPE)/V(transposed) bf16 (round-7 validated;
//                 z<2 LDS XOR upgraded <<3 -> <<4, validated in round 8:
//                 bank conflicts 917K -> ~400K)
//   final_mode=1: fp32 out + bias, NEW half-tile LDS bounce -> 1KB-contiguous
//                 dwordx4 stores (was 4x64B segments per wave-instr)
// ---------------------------------------------------------------------------
__global__ __launch_bounds__(256, 2)
void gemm_bt(const unsigned short* __restrict__ Abase,
             const unsigned short* __restrict__ Bbase,
             const float* __restrict__ b0, const float* __restrict__ b1,
             const float* __restrict__ b2,
             unsigned short* __restrict__ qb, unsigned short* __restrict__ kb,
             unsigned short* __restrict__ vtb,
             float* __restrict__ outf,
             const float* __restrict__ cosc, const float* __restrict__ sinc,
             int final_mode)
{
  __shared__ __attribute__((aligned(16))) unsigned short Sh[2][8192]; // As | Bs
  unsigned short* As = &Sh[0][0];
  unsigned short* Bs = &Sh[1][0];

  const int tid = threadIdx.x;
  const int lane = tid & 63;
  const int wave = tid >> 6;
  const int quad = lane >> 4;
  const int l15 = lane & 15;

  const int z = blockIdx.z;
  const int tileM = blockIdx.x * 128;   // M fastest -> XCD-local A reuse
  const int tileN = blockIdx.y * 128;
  const int K = 1024;

  const unsigned short* A = Abase + (size_t)z * (8192u * 1024u);
  const unsigned short* B = Bbase + (size_t)z * (1024u * 1024u);

  const int wm = (wave >> 1) * 64;
  const int wn = (wave & 1) * 64;

  f32x4 acc[4][4];
#pragma unroll
  for (int a = 0; a < 4; a++)
#pragma unroll
    for (int n = 0; n < 4; n++)
      acc[a][n] = (f32x4){0.f, 0.f, 0.f, 0.f};

  for (int k0 = 0; k0 < K; k0 += 64) {
    // stage 16KB A-tile + 16KB B-tile; each wave: 4 A-chunks + 4 B-chunks
#pragma unroll
    for (int cc = 0; cc < 4; cc++) {
      int c = wave * 4 + cc;           // chunk 0..15 (wave-uniform)
      int s = c * 64 + lane;           // granule slot 0..1023
      int row = s >> 3;                // 8 granules (of 8 bf16) per row
      int gc = (s & 7) ^ (row & 7);    // XOR swizzle: read groups spread banks
      const unsigned short* ga = A + (size_t)(tileM + row) * K + k0 + gc * 8;
      const unsigned short* gb = B + (size_t)(tileN + row) * K + k0 + gc * 8;
      GLOAD_LDS16(ga, &As[c * 512]);
      GLOAD_LDS16(gb, &Bs[c * 512]);
    }
    __syncthreads();   // compiler inserts vmcnt(0) drain before barrier

#pragma unroll
    for (int ks = 0; ks < 2; ks++) {
      bf16x8 af[4], bfr[4];
#pragma unroll
      for (int a = 0; a < 4; a++) {
        int r = wm + a * 16 + l15;
        int cp = (ks * 4 + quad) ^ (r & 7);
        af[a] = *(const bf16x8*)&As[(r * 8 + cp) * 8];
      }
#pragma unroll
      for (int n = 0; n < 4; n++) {
        int r = wn + n * 16 + l15;
        int cp = (ks * 4 + quad) ^ (r & 7);
        bfr[n] = *(const bf16x8*)&Bs[(r * 8 + cp) * 8];
      }
#pragma unroll
      for (int a = 0; a < 4; a++)
#pragma unroll
        for (int n = 0; n < 4; n++)
          acc[a][n] = __builtin_amdgcn_mfma_f32_16x16x32_bf16(af[a], bfr[n], acc[a][n], 0, 0, 0);
    }
    __syncthreads();   // protect LDS for next stage
  }

  // ---------------- epilogue ----------------
  if (final_mode) {
    // fp32 out + bias via half-tile LDS bounce. Half h (64 rows x 128 cols,
    // 32KB) is produced entirely by waves with (wave>>1)==h (cols split by
    // wn, no overlap); all 4 waves then store it fully coalesced.
    float* flatf = (float*)&Sh[0][0];   // 8192 floats
#pragma unroll
    for (int h = 0; h < 2; h++) {
      __syncthreads();
      if ((wave >> 1) == h) {
#pragma unroll
        for (int n = 0; n < 4; n++) {
          int lcg = wn + n * 16 + l15;
          float bias = b0[tileN + lcg];
#pragma unroll
          for (int a = 0; a < 4; a++)
#pragma unroll
            for (int reg = 0; reg < 4; reg++) {
              int lrow = a * 16 + quad * 4 + reg;   // 0..63 within half
              flatf[lrow * 128 + lcg] = acc[a][n][reg] + bias;
            }
        }
      }
      __syncthreads();
#pragma unroll
      for (int c = 0; c < 8; c++) {
        int ff = (c * 256 + tid) * 4;          // 16B chunks, wave-contiguous
        int row = ff >> 7, col = ff & 127;
        *(f32x4*)&outf[(size_t)(tileM + h * 64 + row) * 1024 + tileN + col] =
            *(const f32x4*)&flatf[ff];
      }
    }
  } else {
    // QKV: stage results into the freed 32KB LDS (bank-XOR'd), then store
    // coalesced 16B chunks (round-7 validated; <<4 variant round-8 validated).
    const float* bias = (z == 0) ? b0 : (z == 1) ? b1 : b2;
    unsigned short* outq = (z == 0) ? qb : kb;
    unsigned short* flat = &Sh[0][0];   // 16384 shorts

#pragma unroll
    for (int n = 0; n < 4; n++) {
      int lcg = wn + n * 16 + l15;          // 0..127 (local out column)
      float bv_ = bias[tileN + lcg];
      int e = lcg & 63;
#pragma unroll
      for (int a = 0; a < 4; a++)
#pragma unroll
        for (int reg = 0; reg < 4; reg++) {
          int l = wm + a * 16 + quad * 4 + reg;   // 0..127 (local row)
          float v = acc[a][n][reg] + bv_;
          unsigned short ov;
          int f;
          if (z == 2) {
            ov = f2bf(v);
            f = lcg * 128 + l;
            f ^= ((f >> 7) & 15) << 3;          // ~2-way LDS writes
          } else {
            // fused RoPE: cols sit in lane pairs (lane^1 = col^1)
            float other = __shfl_xor(v, 1);
            float cs = cosc[l * 32 + (e >> 1)];
            float sn = sinc[l * 32 + (e >> 1)];
            ov = f2bf(v * cs + ((e & 1) ? other : -other) * sn);
            f = ((lcg >> 6) << 13) + (l << 6) + e;
            f ^= ((f >> 8) & 7) << 4;           // quads -> disjoint 8-bank groups
          }
          flat[f] = ov;
        }
    }
    __syncthreads();

    unsigned short* gout = ((z == 2) ? vtb : outq) +
                           ((size_t)(tileM >> 7) * 16 + (tileN >> 6)) * 8192;
#pragma unroll
    for (int c = 0; c < 8; c++) {
      int f0 = tid * 64 + c * 8;               // chunk-aligned; XOR keeps chunks whole
      int s0 = (z == 2) ? (f0 ^ (((f0 >> 7) & 15) << 3))
                        : (f0 ^ (((f0 >> 8) & 7) << 4));
      *(u16x8*)&gout[f0] = *(const u16x8*)&flat[s0];
    }
  }
}

// ---------------------------------------------------------------------------
// K4: attention. One block per (b,h). Scores in registers, in-register row
// softmax (16-lane shuffle reduce), fp32 attn out, P via LDS into PV MFMA.
// ---------------------------------------------------------------------------
__global__ __launch_bounds__(256, 2)
void attn_kernel(const unsigned short* __restrict__ qb,
                 const unsigned short* __restrict__ kb,
                 const unsigned short* __restrict__ vtb,
                 const unsigned char* __restrict__ mask,
                 float* __restrict__ attn_out,
                 unsigned short* __restrict__ ob)
{
  __shared__ __attribute__((aligned(16))) unsigned short Pb[128 * 136]; // +8 pad
  const int tid = threadIdx.x;
  const int lane = tid & 63;
  const int wave = tid >> 6;
  const int quad = lane >> 4;
  const int l15 = lane & 15;
  const int bh = blockIdx.x;       // b*16 + h
  const int b = bh >> 4;
  const int h = bh & 15;

  const unsigned short* q = qb + (size_t)bh * 128 * 64;
  const unsigned short* k = kb + (size_t)bh * 128 * 64;
  const unsigned short* vt = vtb + (size_t)bh * 64 * 128;

  f32x4 sacc[2][8];
#pragma unroll
  for (int mt = 0; mt < 2; mt++)
#pragma unroll
    for (int nt = 0; nt < 8; nt++)
      sacc[mt][nt] = (f32x4){0.f, 0.f, 0.f, 0.f};

#pragma unroll
  for (int ks = 0; ks < 2; ks++) {
    bf16x8 aq[2], bk[8];
#pragma unroll
    for (int mt = 0; mt < 2; mt++)
      aq[mt] = *(const bf16x8*)&q[(size_t)(wave * 32 + mt * 16 + l15) * 64 + ks * 32 + quad * 8];
#pragma unroll
    for (int nt = 0; nt < 8; nt++)
      bk[nt] = *(const bf16x8*)&k[(size_t)(nt * 16 + l15) * 64 + ks * 32 + quad * 8];
#pragma unroll
    for (int mt = 0; mt < 2; mt++)
#pragma unroll
      for (int nt = 0; nt < 8; nt++)
        sacc[mt][nt] = __builtin_amdgcn_mfma_f32_16x16x32_bf16(aq[mt], bk[nt], sacc[mt][nt], 0, 0, 0);
  }

  const float scale = 0.125f;
#pragma unroll
  for (int mt = 0; mt < 2; mt++) {
#pragma unroll
    for (int reg = 0; reg < 4; reg++) {
      int r = wave * 32 + mt * 16 + quad * 4 + reg;
      const unsigned char* mrow = mask + ((size_t)b * 128 + r) * 128;
      float sv[8];
#pragma unroll
      for (int nt = 0; nt < 8; nt++) {
        float x = sacc[mt][nt][reg] * scale;
        if (mrow[nt * 16 + l15]) x = -__builtin_inff();
        sv[nt] = x;
      }
      float m = sv[0];
#pragma unroll
      for (int nt = 1; nt < 8; nt++) m = fmaxf(m, sv[nt]);
#pragma unroll
      for (int off = 1; off < 16; off <<= 1) m = fmaxf(m, __shfl_xor(m, off));
      float s = 0.f;
#pragma unroll
      for (int nt = 0; nt < 8; nt++) { sv[nt] = __expf(sv[nt] - m); s += sv[nt]; }
#pragma unroll
      for (int off = 1; off < 16; off <<= 1) s += __shfl_xor(s, off);
      float inv = 1.0f / s;
      float* arow = attn_out + ((size_t)bh * 128 + r) * 128;
#pragma unroll
      for (int nt = 0; nt < 8; nt++) {
        float p = sv[nt] * inv;
        arow[nt * 16 + l15] = p;                    // required fp32 attn output
        Pb[r * 136 + nt * 16 + l15] = f2bf(p);      // bf16 P for PV MFMA
      }
    }
  }
  __syncthreads();

  f32x4 oacc[2][4];
#pragma unroll
  for (int mt = 0; mt < 2; mt++)
#pragma unroll
    for (int nt = 0; nt < 4; nt++)
      oacc[mt][nt] = (f32x4){0.f, 0.f, 0.f, 0.f};

#pragma unroll
  for (int ks = 0; ks < 4; ks++) {
    bf16x8 bv[4], ap[2];
#pragma unroll
    for (int nt = 0; nt < 4; nt++)
      bv[nt] = *(const bf16x8*)&vt[(size_t)(nt * 16 + l15) * 128 + ks * 32 + quad * 8];
#pragma unroll
    for (int mt = 0; mt < 2; mt++)
      ap[mt] = *(const bf16x8*)&Pb[(size_t)(wave * 32 + mt * 16 + l15) * 136 + ks * 32 + quad * 8];
#pragma unroll
    for (int mt = 0; mt < 2; mt++)
#pragma unroll
      for (int nt = 0; nt < 4; nt++)
        oacc[mt][nt] = __builtin_amdgcn_mfma_f32_16x16x32_bf16(ap[mt], bv[nt], oacc[mt][nt], 0, 0, 0);
  }

#pragma unroll
  for (int mt = 0; mt < 2; mt++)
#pragma unroll
    for (int nt = 0; nt < 4; nt++)
#pragma unroll
      for (int reg = 0; reg < 4; reg++) {
        int r = wave * 32 + mt * 16 + quad * 4 + reg;   // l
        int e = nt * 16 + l15;
        ob[((size_t)b * 128 + r) * 1024 + h * 64 + e] = f2bf(oacc[mt][nt][reg]);
      }
}

// ---------------------------------------------------------------------------
extern "C" void kernel_launch(void* const* d_in, const int* in_sizes, int n_in,
                              void* d_out, int out_size, void* d_ws, size_t ws_size,
                              hipStream_t stream)
{
  const float* queries = (const float*)d_in[0];
  const float* keys    = (const float*)d_in[1];
  const float* values  = (const float*)d_in[2];
  const unsigned char* mask = (const unsigned char*)d_in[3];
  const float* Wq = (const float*)d_in[4];
  const float* bq = (const float*)d_in[5];
  const float* Wk = (const float*)d_in[6];
  const float* bk = (const float*)d_in[7];
  const float* Wv = (const float*)d_in[8];
  const float* bv = (const float*)d_in[9];
  const float* Wo = (const float*)d_in[10];
  const float* bo = (const float*)d_in[11];
  const float* ping = (const float*)d_in[12];
  const float* pseq = (const float*)d_in[13];

  float* out  = (float*)d_out;           // [8192,1024] fp32
  float* attn = out + 8388608;           // [64,16,128,128] fp32 (64 MB)
  // use the attn region as scratch for bf16 inputs (48 MB); K4 overwrites it
  unsigned short* Xbf = (unsigned short*)attn;

  char* ws = (char*)d_ws;
  unsigned short* Wt  = (unsigned short*)(ws);                          // 8 MB
  float* cosc = (float*)(ws + 8388608);                                 // 16 KB
  float* sinc = (float*)(ws + 8388608 + 16384);                         // 16 KB
  unsigned short* qbuf = (unsigned short*)(ws + 8421376);               // 16 MB
  unsigned short* kbuf = (unsigned short*)(ws + 8421376 + 16777216);    // 16 MB
  unsigned short* vtbuf= (unsigned short*)(ws + 8421376 + 2*16777216);  // 16 MB
  unsigned short* obuf = (unsigned short*)(ws + 8421376 + 3*16777216);  // 16 MB

  prep_all<<<dim3(25616), 256, 0, stream>>>(queries, keys, values,
                                            Wq, Wk, Wv, Wo, ping, pseq,
                                            Xbf, Wt, cosc, sinc);
  gemm_bt<<<dim3(64, 8, 3), 256, 0, stream>>>(Xbf, Wt, bq, bk, bv,
                                              qbuf, kbuf, vtbuf, nullptr,
                                              cosc, sinc, 0);
  attn_kernel<<<dim3(1024), 256, 0, stream>>>(qbuf, kbuf, vtbuf, mask, attn, obuf);
  gemm_bt<<<dim3(64, 8, 1), 256, 0, stream>>>(obuf, Wt + 3 * 1048576, bo, bo, bo,
                                              qbuf, kbuf, vtbuf, out,
                                              cosc, sinc, 1);
}